// Round 1
// baseline (419.212 us; speedup 1.0000x reference)
//
#include <hip/hip_runtime.h>
#include <stdint.h>
#include <math.h>

typedef __bf16 bf16;
typedef __bf16 bf16x4 __attribute__((ext_vector_type(4)));
typedef __bf16 bf16x8 __attribute__((ext_vector_type(8)));
typedef float  f32x4  __attribute__((ext_vector_type(4)));

#define B_DIM 8192
#define K_DIM 4096
#define N_DIM 4096
// hash constants
#define MEM_H 1048576
#define HMOD  1047552   // MEM_H - 32*32

// ---------------- host-side numpy legacy RNG replication ----------------
// np.random.RandomState(seed).randint(1, 2**31-1, size=3) on int64 dtype:
// legacy masked-rejection path; range 2^31-2 fits 32 bits -> one 32-bit
// tempered MT19937 draw per value, mask 0x7FFFFFFF, reject > 2^31-3.
static void mt_randint3(uint32_t seed, long long R[3]) {
  uint32_t mt[624];
  mt[0] = seed;
  for (int i = 1; i < 624; i++)
    mt[i] = 1812433253u * (mt[i - 1] ^ (mt[i - 1] >> 30)) + (uint32_t)i;
  int pos = 624;
  auto next32 = [&]() -> uint32_t {
    if (pos >= 624) {
      for (int i = 0; i < 624; i++) {
        uint32_t y = (mt[i] & 0x80000000u) | (mt[(i + 1) % 624] & 0x7fffffffu);
        uint32_t v = mt[(i + 397) % 624] ^ (y >> 1);
        if (y & 1u) v ^= 0x9908b0dfu;
        mt[i] = v;
      }
      pos = 0;
    }
    uint32_t y = mt[pos++];
    y ^= y >> 11;
    y ^= (y << 7) & 0x9d2c5680u;
    y ^= (y << 15) & 0xefc60000u;
    y ^= y >> 18;
    return y;
  };
  for (int j = 0; j < 3; j++) {
    uint32_t v;
    do { v = next32() & 0x7fffffffu; } while (v > 0x7ffffffdu);
    R[j] = 1LL + (long long)v;
  }
}

// ---------------- x: f32 -> bf16 (vectorized) ----------------
__global__ void k_convert_x(const float* __restrict__ x, bf16* __restrict__ xb) {
  int i = blockIdx.x * 256 + threadIdx.x;      // each thread: 8 elements
  const f32x4* p = (const f32x4*)x;
  f32x4 a = p[2 * i], b = p[2 * i + 1];
  bf16x8 o;
  o[0] = (bf16)a[0]; o[1] = (bf16)a[1]; o[2] = (bf16)a[2]; o[3] = (bf16)a[3];
  o[4] = (bf16)b[0]; o[5] = (bf16)b[1]; o[6] = (bf16)b[2]; o[7] = (bf16)b[3];
  ((bf16x8*)xb)[i] = o;
}

// ---------------- build W^T [N][K] bf16 from hashed vector ----------------
// tile (kb,nb): W[kb*32+r][nb*32+c] = hw[start + r*32 + c]
// Wt[nb*32+c][kb*32+r] = same. One block per tile; write-coalesced (64B rows).
__global__ void k_build_wt(const float* __restrict__ hw, bf16* __restrict__ wt,
                           long long R1, long long R2, long long R3) {
  int tile = blockIdx.x;
  int kb = tile & 127, nb = tile >> 7;
  long long v = (long long)kb * R3 + (long long)nb * R2 + R1;
  int start = (int)((v % 2147483647LL) % (long long)HMOD);
  const float* src = hw + start;
  int t  = threadIdx.x;
  int nl = t >> 3;       // 0..31 : c (column within tile) -> Wt row
  int k4 = t & 7;        // 0..7  : group of 4 consecutive r -> Wt cols
  bf16x4 o;
#pragma unroll
  for (int j = 0; j < 4; j++) o[j] = (bf16)src[(k4 * 4 + j) * 32 + nl];
  *(bf16x4*)(wt + (size_t)(nb * 32 + nl) * K_DIM + kb * 32 + k4 * 4) = o;
}

// ---------------- GEMM 128x128xK, fused row sum-of-squares ----------------
// A: x_bf16 [B][K] row-major. Bt: W^T [N][K] row-major.
// partial[(nt*2+wn)*B_DIM + row] = sum over this block's 64-col half of y^2.
__device__ __forceinline__ void gload_lds16(const void* g, void* l) {
  __builtin_amdgcn_global_load_lds(
      (const __attribute__((address_space(1))) void*)g,
      (__attribute__((address_space(3))) void*)l, 16, 0, 0);
}

__global__ __launch_bounds__(256) void k_gemm(const bf16* __restrict__ A,
                                              const bf16* __restrict__ Bt,
                                              float* __restrict__ partial) {
  __shared__ bf16 lA[128 * 32];   // 8 KB, row-major [m][k]
  __shared__ bf16 lB[128 * 32];   // 8 KB, row-major [n][k]
  int bid = blockIdx.x;
  // XCD-aware swizzle: 2048 blocks, 8 XCDs -> bijective
  int swz = (bid & 7) * 256 + (bid >> 3);
  int mt = swz & 63, nt = swz >> 6;      // m fastest: B n-panel stays L2-hot
  int tid = threadIdx.x;
  int w = tid >> 6, lane = tid & 63;
  int wm = w >> 1, wn = w & 1;           // 2x2 wave grid, each 64x64
  int lr = lane & 15, lk = lane >> 4;
  size_t bm = (size_t)mt * 128, bn = (size_t)nt * 128;
  const bf16* Ab = A + bm * K_DIM;
  const bf16* Bb = Bt + bn * K_DIM;
  f32x4 acc[4][4] = {};

  for (int kt = 0; kt < K_DIM; kt += 32) {
#pragma unroll
    for (int j = 0; j < 2; j++) {
      int cid = j * 256 + tid;           // 512 chunks of 8 bf16 per tile
      int m = cid >> 2, kc = cid & 3;
      gload_lds16(Ab + (size_t)m * K_DIM + kt + kc * 8,
                  lA + (size_t)(j * 256 + w * 64) * 8);
      gload_lds16(Bb + (size_t)m * K_DIM + kt + kc * 8,
                  lB + (size_t)(j * 256 + w * 64) * 8);
    }
    __syncthreads();
    bf16x8 af[4], bg[4];
#pragma unroll
    for (int mi = 0; mi < 4; mi++)
      af[mi] = *(const bf16x8*)&lA[(wm * 64 + mi * 16 + lr) * 32 + lk * 8];
#pragma unroll
    for (int ni = 0; ni < 4; ni++)
      bg[ni] = *(const bf16x8*)&lB[(wn * 64 + ni * 16 + lr) * 32 + lk * 8];
#pragma unroll
    for (int mi = 0; mi < 4; mi++)
#pragma unroll
      for (int ni = 0; ni < 4; ni++)
        acc[mi][ni] = __builtin_amdgcn_mfma_f32_16x16x32_bf16(
            af[mi], bg[ni], acc[mi][ni], 0, 0, 0);
    __syncthreads();
  }

  // epilogue: per-row sum of squares over this block's 64-col wave half
  // C layout (verified m89/m91): col = lane&15, row = (lane>>4)*4 + reg
#pragma unroll
  for (int mi = 0; mi < 4; mi++) {
#pragma unroll
    for (int r = 0; r < 4; r++) {
      float s = 0.f;
#pragma unroll
      for (int ni = 0; ni < 4; ni++) { float vv = acc[mi][ni][r]; s += vv * vv; }
      s += __shfl_xor(s, 1);
      s += __shfl_xor(s, 2);
      s += __shfl_xor(s, 4);
      s += __shfl_xor(s, 8);
      if (lr == 0) {
        int row = (int)bm + wm * 64 + mi * 16 + lk * 4 + r;
        partial[(size_t)(nt * 2 + wn) * B_DIM + row] = s;
      }
    }
  }
}

// ---------------- finish: sum 64 partials per row, sqrt ----------------
__global__ void k_finish(const float* __restrict__ partial, float* __restrict__ out) {
  int b = blockIdx.x * 256 + threadIdx.x;
  float s = 0.f;
#pragma unroll
  for (int i = 0; i < 64; i++) s += partial[(size_t)i * B_DIM + b];
  out[b] = sqrtf(s);
}

extern "C" void kernel_launch(void* const* d_in, const int* in_sizes, int n_in,
                              void* d_out, int out_size, void* d_ws, size_t ws_size,
                              hipStream_t stream) {
  const float* x  = (const float*)d_in[0];
  const float* hw = (const float*)d_in[1];
  float* out = (float*)d_out;
  char* ws = (char*)d_ws;
  bf16* xb = (bf16*)ws;                                           // 64 MB
  bf16* wt = (bf16*)(ws + (size_t)B_DIM * K_DIM * 2);             // 32 MB
  float* partial = (float*)(ws + (size_t)B_DIM * K_DIM * 2
                               + (size_t)K_DIM * N_DIM * 2);      // 2 MB

  long long R[3];
  mt_randint3(1367u, R);

  k_convert_x<<<(B_DIM * K_DIM) / (256 * 8), 256, 0, stream>>>(x, xb);
  k_build_wt<<<(K_DIM / 32) * (N_DIM / 32), 256, 0, stream>>>(hw, wt, R[0], R[1], R[2]);
  k_gemm<<<(B_DIM / 128) * (N_DIM / 128), 256, 0, stream>>>(xb, wt, partial);
  k_finish<<<B_DIM / 256, 256, 0, stream>>>(partial, out);
}

// Round 2
// 287.289 us; speedup vs baseline: 1.4592x; 1.4592x over previous
//
#include <hip/hip_runtime.h>
#include <stdint.h>
#include <math.h>

typedef __bf16 bf16;
typedef __bf16 bf16x4 __attribute__((ext_vector_type(4)));
typedef __bf16 bf16x8 __attribute__((ext_vector_type(8)));
typedef float  f32x4  __attribute__((ext_vector_type(4)));

#define B_DIM 8192
#define K_DIM 4096
#define N_DIM 4096
#define MEM_H 1048576
#define HMOD  1047552   // MEM_H - 32*32
#define NT    (K_DIM / 64)

// ---------------- host-side numpy legacy RNG replication ----------------
static void mt_randint3(uint32_t seed, long long R[3]) {
  uint32_t mt[624];
  mt[0] = seed;
  for (int i = 1; i < 624; i++)
    mt[i] = 1812433253u * (mt[i - 1] ^ (mt[i - 1] >> 30)) + (uint32_t)i;
  int pos = 624;
  auto next32 = [&]() -> uint32_t {
    if (pos >= 624) {
      for (int i = 0; i < 624; i++) {
        uint32_t y = (mt[i] & 0x80000000u) | (mt[(i + 1) % 624] & 0x7fffffffu);
        uint32_t v = mt[(i + 397) % 624] ^ (y >> 1);
        if (y & 1u) v ^= 0x9908b0dfu;
        mt[i] = v;
      }
      pos = 0;
    }
    uint32_t y = mt[pos++];
    y ^= y >> 11;
    y ^= (y << 7) & 0x9d2c5680u;
    y ^= (y << 15) & 0xefc60000u;
    y ^= y >> 18;
    return y;
  };
  for (int j = 0; j < 3; j++) {
    uint32_t v;
    do { v = next32() & 0x7fffffffu; } while (v > 0x7ffffffdu);
    R[j] = 1LL + (long long)v;
  }
}

// ---------------- x: f32 -> bf16 (vectorized) ----------------
__global__ void k_convert_x(const float* __restrict__ x, bf16* __restrict__ xb) {
  int i = blockIdx.x * 256 + threadIdx.x;
  const f32x4* p = (const f32x4*)x;
  f32x4 a = p[2 * i], b = p[2 * i + 1];
  bf16x8 o;
  o[0] = (bf16)a[0]; o[1] = (bf16)a[1]; o[2] = (bf16)a[2]; o[3] = (bf16)a[3];
  o[4] = (bf16)b[0]; o[5] = (bf16)b[1]; o[6] = (bf16)b[2]; o[7] = (bf16)b[3];
  ((bf16x8*)xb)[i] = o;
}

// ---------------- build W^T [N][K] bf16 from hashed vector ----------------
__global__ void k_build_wt(const float* __restrict__ hw, bf16* __restrict__ wt,
                           long long R1, long long R2, long long R3) {
  int tile = blockIdx.x;
  int kb = tile & 127, nb = tile >> 7;
  long long v = (long long)kb * R3 + (long long)nb * R2 + R1;
  int start = (int)((v % 2147483647LL) % (long long)HMOD);
  const float* src = hw + start;
  int t  = threadIdx.x;
  int nl = t >> 3;
  int k4 = t & 7;
  bf16x4 o;
#pragma unroll
  for (int j = 0; j < 4; j++) o[j] = (bf16)src[(k4 * 4 + j) * 32 + nl];
  *(bf16x4*)(wt + (size_t)(nb * 32 + nl) * K_DIM + kb * 32 + k4 * 4) = o;
}

// ---------------- 256x256x64 8-phase GEMM, fused row sum-of-squares ------
__device__ __forceinline__ void gload_lds16(const void* g, void* l) {
  __builtin_amdgcn_global_load_lds(
      (const __attribute__((address_space(1))) void*)g,
      (__attribute__((address_space(3))) void*)l, 16, 0, 0);
}

#define ASM_VMCNT2() asm volatile("s_waitcnt vmcnt(2)" ::: "memory")
#define ASM_VMCNT0() asm volatile("s_waitcnt vmcnt(0)" ::: "memory")
#define BAR() asm volatile("s_barrier" ::: "memory")

#define MM(rh, ch) do {                                                        \
  __builtin_amdgcn_s_setprio(1);                                               \
  _Pragma("unroll")                                                            \
  for (int ks = 0; ks < 2; ks++)                                               \
    _Pragma("unroll")                                                          \
    for (int r4 = 0; r4 < 4; r4++)                                             \
      _Pragma("unroll")                                                        \
      for (int c2 = 0; c2 < 2; c2++)                                           \
        acc[(rh)*4 + r4][(ch)*2 + c2] =                                        \
            __builtin_amdgcn_mfma_f32_16x16x32_bf16(                           \
                af[r4][ks], bg[(ch)*2 + c2][ks],                               \
                acc[(rh)*4 + r4][(ch)*2 + c2], 0, 0, 0);                       \
  __builtin_amdgcn_s_setprio(0);                                               \
} while (0)

__global__ __launch_bounds__(512, 2) void k_gemm(const bf16* __restrict__ A,
                                                 const bf16* __restrict__ Bt,
                                                 float* __restrict__ partial) {
  // [buf][op 0=A 1=B][half][128*64] : 128 KiB
  __shared__ bf16 sm[2][2][2][128 * 64];
  int bid = blockIdx.x;
  int swz = (bid & 7) * 64 + (bid >> 3);     // 512 blocks, 8 XCDs, bijective
  int mt = swz & 31, nt = swz >> 5;
  int tid = threadIdx.x;
  int w = tid >> 6, lane = tid & 63;
  int wm = w >> 2, wn = w & 3;               // 2 x 4 wave grid, 128x64 each
  int lr = lane & 15, lk = lane >> 4;
  int r8 = lane >> 3, gg = lane & 7;
  int swcol = ((gg ^ r8) << 3);              // pre-swizzled source col (elems)
  size_t bm = (size_t)mt * 256, bn = (size_t)nt * 256;
  const bf16* Ab = A + bm * K_DIM;
  const bf16* Bb = Bt + bn * K_DIM;

  f32x4 acc[8][4] = {};
  bf16x8 af[4][2], bg[4][2];

  // stage one half-tile (128 rows x 64 k): g points at (row0, k0) of the half
  auto STAGE = [&](const bf16* g, bf16* lds) {
    gload_lds16(g + (size_t)(w * 8 + r8) * K_DIM + swcol, lds + (w * 8) * 64);
    gload_lds16(g + (size_t)(64 + w * 8 + r8) * K_DIM + swcol,
                lds + (64 + w * 8) * 64);
  };
  // swizzled fragment reads
  auto RDA = [&](int buf, int rb, int ks) -> bf16x8 {
    const bf16* h = &sm[buf][0][wm][0];
    int row = rb * 16 + lr;
    int gc = ks * 4 + lk;
    return *(const bf16x8*)(h + row * 64 + ((gc ^ (row & 7)) << 3));
  };
  auto RDB = [&](int buf, int cb, int ks) -> bf16x8 {
    const bf16* h = &sm[buf][1][wn >> 1][0];
    int row = (wn & 1) * 64 + cb * 16 + lr;
    int gc = ks * 4 + lk;
    return *(const bf16x8*)(h + row * 64 + ((gc ^ (row & 7)) << 3));
  };

  // prologue: tile0 (4 halves) + A-h0(tile1); boundary vmcnt(2)
  STAGE(Ab, &sm[0][0][0][0]);
  STAGE(Ab + (size_t)128 * K_DIM, &sm[0][0][1][0]);
  STAGE(Bb, &sm[0][1][0][0]);
  STAGE(Bb + (size_t)128 * K_DIM, &sm[0][1][1][0]);
  STAGE(Ab + 64, &sm[1][0][0][0]);
  ASM_VMCNT2();
  BAR();

  for (int t = 0; t < NT; t++) {
    int cur = t & 1, nxt = cur ^ 1;
    const bf16* An = Ab + (size_t)(t + 1) * 64;
    const bf16* Bn = Bb + (size_t)(t + 1) * 64;

    // ---- phase 0: read A rows0-3 + B cols0-1; stage B-h0(t+1) ----
#pragma unroll
    for (int rb = 0; rb < 4; rb++) {
      af[rb][0] = RDA(cur, rb, 0);
      af[rb][1] = RDA(cur, rb, 1);
    }
#pragma unroll
    for (int cb = 0; cb < 2; cb++) {
      bg[cb][0] = RDB(cur, cb, 0);
      bg[cb][1] = RDB(cur, cb, 1);
    }
    if (t + 1 < NT) STAGE(Bn, &sm[nxt][1][0][0]);
    BAR();
    MM(0, 0);
    BAR();

    // ---- phase 1: read B cols2-3; stage B-h1(t+1) ----
#pragma unroll
    for (int cb = 2; cb < 4; cb++) {
      bg[cb][0] = RDB(cur, cb, 0);
      bg[cb][1] = RDB(cur, cb, 1);
    }
    if (t + 1 < NT) STAGE(Bn + (size_t)128 * K_DIM, &sm[nxt][1][1][0]);
    BAR();
    MM(0, 1);
    BAR();

    // ---- phase 2: read A rows4-7 (reuse af regs); stage A-h1(t+1) ----
#pragma unroll
    for (int rb = 0; rb < 4; rb++) {
      af[rb][0] = RDA(cur, 4 + rb, 0);
      af[rb][1] = RDA(cur, 4 + rb, 1);
    }
    if (t + 1 < NT) STAGE(An + (size_t)128 * K_DIM, &sm[nxt][0][1][0]);
    BAR();
    MM(1, 0);
    BAR();

    // ---- phase 3: no reads; stage A-h0(t+2) (same buf: A reads done @ph2) ----
    if (t + 2 < NT) STAGE(Ab + (size_t)(t + 2) * 64, &sm[cur][0][0][0]);
    BAR();
    MM(1, 1);
    if (t < NT - 2) ASM_VMCNT2(); else ASM_VMCNT0();
    BAR();
  }

  // epilogue: per-row sum of squares over this wave's 64 cols
  // C frag: col = cb*16 + (lane&15), row = rb*16 + (lane>>4)*4 + reg
#pragma unroll
  for (int rb = 0; rb < 8; rb++) {
#pragma unroll
    for (int reg = 0; reg < 4; reg++) {
      float s = 0.f;
#pragma unroll
      for (int cb = 0; cb < 4; cb++) { float v = acc[rb][cb][reg]; s += v * v; }
      s += __shfl_xor(s, 1);
      s += __shfl_xor(s, 2);
      s += __shfl_xor(s, 4);
      s += __shfl_xor(s, 8);
      if (lr == 0) {
        int row = (int)bm + wm * 128 + rb * 16 + lk * 4 + reg;
        partial[(size_t)(nt * 4 + wn) * B_DIM + row] = s;
      }
    }
  }
}

// ---------------- finish: sum 64 partials per row, sqrt ----------------
__global__ void k_finish(const float* __restrict__ partial, float* __restrict__ out) {
  int b = blockIdx.x * 256 + threadIdx.x;
  float s = 0.f;
#pragma unroll
  for (int i = 0; i < 64; i++) s += partial[(size_t)i * B_DIM + b];
  out[b] = sqrtf(s);
}

extern "C" void kernel_launch(void* const* d_in, const int* in_sizes, int n_in,
                              void* d_out, int out_size, void* d_ws, size_t ws_size,
                              hipStream_t stream) {
  const float* x  = (const float*)d_in[0];
  const float* hw = (const float*)d_in[1];
  float* out = (float*)d_out;
  char* ws = (char*)d_ws;
  bf16* xb = (bf16*)ws;                                           // 64 MB
  bf16* wt = (bf16*)(ws + (size_t)B_DIM * K_DIM * 2);             // 32 MB
  float* partial = (float*)(ws + (size_t)B_DIM * K_DIM * 2
                               + (size_t)K_DIM * N_DIM * 2);      // 2 MB

  long long R[3];
  mt_randint3(1367u, R);

  k_convert_x<<<(B_DIM * K_DIM) / (256 * 8), 256, 0, stream>>>(x, xb);
  k_build_wt<<<(K_DIM / 32) * (N_DIM / 32), 256, 0, stream>>>(hw, wt, R[0], R[1], R[2]);
  k_gemm<<<(B_DIM / 256) * (N_DIM / 256), 512, 0, stream>>>(xb, wt, partial);
  k_finish<<<B_DIM / 256, 256, 0, stream>>>(partial, out);
}